// Round 2
// baseline (1405.381 us; speedup 1.0000x reference)
//
#include <hip/hip_runtime.h>
#include <stdint.h>

#define NROWS 131072
#define NC 1024
#define ND 512
#define BM 64
#define NSTEP 32   // 16 K-steps for B-hi pass + 16 for B-lo pass

using f32x4   = __attribute__((ext_vector_type(4))) float;
using bf16x8  = __attribute__((ext_vector_type(8))) short;
using short4v = __attribute__((ext_vector_type(4))) short;
using float4v = __attribute__((ext_vector_type(4))) float;

__device__ __forceinline__ uint16_t f32_bf16(float f) {
  uint32_t u = __builtin_bit_cast(uint32_t, f);
  u += 0x7FFFu + ((u >> 16) & 1u);   // RNE
  return (uint16_t)(u >> 16);
}
__device__ __forceinline__ float bf16_f32(uint16_t h) {
  uint32_t u = ((uint32_t)h) << 16;
  return __builtin_bit_cast(float, u);
}

__device__ __forceinline__ void gload_lds16(const void* g, void* l) {
  __builtin_amdgcn_global_load_lds(
      (const __attribute__((address_space(1))) unsigned int*)g,
      (__attribute__((address_space(3))) unsigned int*)l, 16, 0, 0);
}

// ---------------------------------------------------------------------------
// Prep: split centers into bf16 hi/lo, pre-permuted so that each K-step slice
// is a contiguous 64KB block whose LINEAR copy into LDS yields the swizzled
// layout: LDS[c*64 + p*16 + b] holds logical chunk j = p ^ (c&3) of row c.
// Also computes csq[c] = sum(c^2) in fp32.
// ---------------------------------------------------------------------------
__global__ __launch_bounds__(64) void prep_centers(
    const float* __restrict__ centers,
    uint16_t* __restrict__ cs_hi, uint16_t* __restrict__ cs_lo,
    float* __restrict__ csq) {
  const int c = blockIdx.x;   // 1024
  const int t = threadIdx.x;  // 64
  const float* row = centers + (size_t)c * ND;
  const int k0 = t * 8;
  float v[8];
#pragma unroll
  for (int i = 0; i < 8; ++i) v[i] = row[k0 + i];
  float ss = 0.f;
#pragma unroll
  for (int i = 0; i < 8; ++i) ss += v[i] * v[i];
#pragma unroll
  for (int m = 1; m < 64; m <<= 1) ss += __shfl_xor(ss, m);
  if (t == 0) csq[c] = ss;

  const int kk = t >> 2;          // K-step 0..15
  const int j  = t & 3;           // logical 16B chunk within K-step
  const int p  = j ^ (c & 3);     // physical chunk (XOR swizzle)
  const size_t off = (size_t)kk * 32768 + (size_t)c * 32 + (size_t)p * 8;
#pragma unroll
  for (int i = 0; i < 8; ++i) {
    uint16_t h = f32_bf16(v[i]);
    uint16_t l = f32_bf16(v[i] - bf16_f32(h));
    cs_hi[off + i] = h;
    cs_lo[off + i] = l;
  }
}

// ---------------------------------------------------------------------------
// Fused kernel: 64 rows x full 1024 cols per block. 8 waves (2 wm x 4 wn),
// wave tile 32x256, mfma_f32_16x16x32_bf16. Two passes over K:
//   pass H (s<16): B = cs_hi, acc += a_hi*b + a_lo*b
//   pass L (s>=16): B = cs_lo, acc += a_hi*b
// Then epilogue: distances + block-local softmax, both written to global.
// ---------------------------------------------------------------------------
__global__ __launch_bounds__(512) void kmeans_fused(
    const float* __restrict__ x,
    const uint16_t* __restrict__ cs_hi, const uint16_t* __restrict__ cs_lo,
    const float* __restrict__ csq,
    float* __restrict__ dist, float* __restrict__ prob) {
  __shared__ __align__(16) char bs[2][65536];     // 1024 cols x 32 bf16, swizzled
  __shared__ __align__(16) char as_hi[2][4096];   // 64 rows x 32 bf16, swizzled
  __shared__ __align__(16) char as_lo[2][4096];
  __shared__ float xsq[BM];
  __shared__ __align__(16) float red[2][BM][4];

  const int tid  = threadIdx.x;
  const int lane = tid & 63;
  const int wid  = tid >> 6;
  const int wm   = wid >> 2;   // 0..1 -> rows wm*32
  const int wn   = wid & 3;    // 0..3 -> cols wn*256
  const int row0 = blockIdx.x * BM;

  // ---- xsq (exact fp32): 8 threads per row, 64 elems each ----
  {
    const int r = tid >> 3, sub = tid & 7;
    const float* rp = x + (size_t)(row0 + r) * ND + sub * 64;
    float ss = 0.f;
#pragma unroll
    for (int i = 0; i < 16; ++i) {
      float4v v = *(const float4v*)(rp + i * 4);
      ss += v[0] * v[0] + v[1] * v[1] + v[2] * v[2] + v[3] * v[3];
    }
    ss += __shfl_xor(ss, 1);
    ss += __shfl_xor(ss, 2);
    ss += __shfl_xor(ss, 4);
    if (sub == 0) xsq[r] = ss;
  }

  auto stage = [&](int s) {
    const uint16_t* src = (s < 16 ? cs_hi : cs_lo) + (size_t)(s & 15) * 32768;
    const char* srcb = (const char*)src;
    char* dst = bs[s & 1];
#pragma unroll
    for (int i = 0; i < 8; ++i) {
      const int o = (tid + i * 512) * 16;
      gload_lds16(srcb + o, dst + o);
    }
  };
  auto xload = [&](int s) -> float4v {
    const int r = tid >> 3, c = tid & 7;
    return *(const float4v*)(x + (size_t)(row0 + r) * ND + (s & 15) * 32 + c * 4);
  };
  auto awrite = [&](int s, float4v v) {
    const int r = tid >> 3, c = tid & 7;
    const int p = (c >> 1) ^ (r & 3);
    const int off = r * 64 + p * 16 + (c & 1) * 8;
    short4v h, l;
#pragma unroll
    for (int i = 0; i < 4; ++i) {
      uint16_t hb = f32_bf16(v[i]);
      h[i] = (short)hb;
      l[i] = (short)f32_bf16(v[i] - bf16_f32(hb));
    }
    *(short4v*)(as_hi[s & 1] + off) = h;
    *(short4v*)(as_lo[s & 1] + off) = l;
  };

  f32x4 acc[2][16];
  const f32x4 z = {0.f, 0.f, 0.f, 0.f};
#pragma unroll
  for (int mr = 0; mr < 2; ++mr)
#pragma unroll
    for (int n = 0; n < 16; ++n) acc[mr][n] = z;

  // fragment LDS byte offsets (row&3 == lane&3 since bases are mult of 16)
  const int swz  = (((lane >> 4) ^ (lane & 3)) << 4);
  const int aoff = (wm * 32 + (lane & 15)) * 64 + swz;   // + mr*1024
  const int boff = (wn * 256 + (lane & 15)) * 64 + swz;  // + n*1024

  auto compute = [&](int s) {
    const char* bp  = bs[s & 1];
    const char* ahp = as_hi[s & 1];
    bf16x8 ah0 = *(const bf16x8*)(ahp + aoff);
    bf16x8 ah1 = *(const bf16x8*)(ahp + aoff + 1024);
    if (s < 16) {
      const char* alp = as_lo[s & 1];
      bf16x8 al0 = *(const bf16x8*)(alp + aoff);
      bf16x8 al1 = *(const bf16x8*)(alp + aoff + 1024);
#pragma unroll
      for (int n = 0; n < 16; ++n) {
        bf16x8 b = *(const bf16x8*)(bp + boff + n * 1024);
        acc[0][n] = __builtin_amdgcn_mfma_f32_16x16x32_bf16(ah0, b, acc[0][n], 0, 0, 0);
        acc[1][n] = __builtin_amdgcn_mfma_f32_16x16x32_bf16(ah1, b, acc[1][n], 0, 0, 0);
        acc[0][n] = __builtin_amdgcn_mfma_f32_16x16x32_bf16(al0, b, acc[0][n], 0, 0, 0);
        acc[1][n] = __builtin_amdgcn_mfma_f32_16x16x32_bf16(al1, b, acc[1][n], 0, 0, 0);
      }
    } else {
#pragma unroll
      for (int n = 0; n < 16; ++n) {
        bf16x8 b = *(const bf16x8*)(bp + boff + n * 1024);
        acc[0][n] = __builtin_amdgcn_mfma_f32_16x16x32_bf16(ah0, b, acc[0][n], 0, 0, 0);
        acc[1][n] = __builtin_amdgcn_mfma_f32_16x16x32_bf16(ah1, b, acc[1][n], 0, 0, 0);
      }
    }
  };

  // ---- main loop: double-buffered Bs (global_load_lds) + reg-staged As ----
  stage(0);
  {
    float4v v0 = xload(0);
    awrite(0, v0);
  }
  __syncthreads();
#pragma unroll 1
  for (int s = 0; s < NSTEP; ++s) {
    if (s + 1 < NSTEP) {
      stage(s + 1);
      float4v vn = xload(s + 1);
      compute(s);
      awrite(s + 1, vn);
    } else {
      compute(s);
    }
    __syncthreads();
  }

  // ---- epilogue: distances + softmax(-d) ----
  const int rsub = (lane >> 4) * 4;
  const int colbase = wn * 256 + (lane & 15);
  float csqv[16];
#pragma unroll
  for (int n = 0; n < 16; ++n) csqv[n] = csq[colbase + n * 16];
  float xsqv[2][4];
#pragma unroll
  for (int mr = 0; mr < 2; ++mr)
#pragma unroll
    for (int r = 0; r < 4; ++r) xsqv[mr][r] = xsq[wm * 32 + mr * 16 + rsub + r];

  float rmin[2][4];
#pragma unroll
  for (int mr = 0; mr < 2; ++mr)
#pragma unroll
    for (int r = 0; r < 4; ++r) rmin[mr][r] = 1e30f;

#pragma unroll
  for (int mr = 0; mr < 2; ++mr) {
#pragma unroll
    for (int n = 0; n < 16; ++n) {
#pragma unroll
      for (int r = 0; r < 4; ++r) {
        float d = xsqv[mr][r] + csqv[n] - 2.0f * acc[mr][n][r];
        d = fmaxf(d, 0.0f);
        acc[mr][n][r] = d;
        rmin[mr][r] = fminf(rmin[mr][r], d);
        const size_t row = (size_t)(row0 + wm * 32 + mr * 16 + rsub + r);
        dist[row * NC + colbase + n * 16] = d;
      }
    }
  }

  // row-min: reduce over the 16 lanes sharing the same rows, then across wn
#pragma unroll
  for (int mr = 0; mr < 2; ++mr)
#pragma unroll
    for (int r = 0; r < 4; ++r) {
      float v = rmin[mr][r];
      v = fminf(v, __shfl_xor(v, 1));
      v = fminf(v, __shfl_xor(v, 2));
      v = fminf(v, __shfl_xor(v, 4));
      v = fminf(v, __shfl_xor(v, 8));
      rmin[mr][r] = v;
    }
  if ((lane & 15) == 0) {
#pragma unroll
    for (int mr = 0; mr < 2; ++mr)
#pragma unroll
      for (int r = 0; r < 4; ++r)
        red[0][wm * 32 + mr * 16 + rsub + r][wn] = rmin[mr][r];
  }
  __syncthreads();

  float msub[2][4];
#pragma unroll
  for (int mr = 0; mr < 2; ++mr)
#pragma unroll
    for (int r = 0; r < 4; ++r) {
      float4v t = *(const float4v*)&red[0][wm * 32 + mr * 16 + rsub + r][0];
      msub[mr][r] = fminf(fminf(t[0], t[1]), fminf(t[2], t[3]));
    }

  float rsum[2][4];
#pragma unroll
  for (int mr = 0; mr < 2; ++mr)
#pragma unroll
    for (int r = 0; r < 4; ++r) rsum[mr][r] = 0.f;

#pragma unroll
  for (int mr = 0; mr < 2; ++mr)
#pragma unroll
    for (int n = 0; n < 16; ++n)
#pragma unroll
      for (int r = 0; r < 4; ++r) {
        float e = __expf(msub[mr][r] - acc[mr][n][r]);
        acc[mr][n][r] = e;
        rsum[mr][r] += e;
      }

#pragma unroll
  for (int mr = 0; mr < 2; ++mr)
#pragma unroll
    for (int r = 0; r < 4; ++r) {
      float v = rsum[mr][r];
      v += __shfl_xor(v, 1);
      v += __shfl_xor(v, 2);
      v += __shfl_xor(v, 4);
      v += __shfl_xor(v, 8);
      rsum[mr][r] = v;
    }
  if ((lane & 15) == 0) {
#pragma unroll
    for (int mr = 0; mr < 2; ++mr)
#pragma unroll
      for (int r = 0; r < 4; ++r)
        red[1][wm * 32 + mr * 16 + rsub + r][wn] = rsum[mr][r];
  }
  __syncthreads();

  float sinv[2][4];
#pragma unroll
  for (int mr = 0; mr < 2; ++mr)
#pragma unroll
    for (int r = 0; r < 4; ++r) {
      float4v t = *(const float4v*)&red[1][wm * 32 + mr * 16 + rsub + r][0];
      sinv[mr][r] = 1.0f / (t[0] + t[1] + t[2] + t[3]);
    }

#pragma unroll
  for (int mr = 0; mr < 2; ++mr)
#pragma unroll
    for (int n = 0; n < 16; ++n)
#pragma unroll
      for (int r = 0; r < 4; ++r) {
        const size_t row = (size_t)(row0 + wm * 32 + mr * 16 + rsub + r);
        prob[row * NC + colbase + n * 16] = acc[mr][n][r] * sinv[mr][r];
      }
}

extern "C" void kernel_launch(void* const* d_in, const int* in_sizes, int n_in,
                              void* d_out, int out_size, void* d_ws, size_t ws_size,
                              hipStream_t stream) {
  const float* x = (const float*)d_in[0];
  const float* centers = (const float*)d_in[1];
  float* dist = (float*)d_out;
  float* prob = dist + (size_t)NROWS * NC;

  uint16_t* cs_hi = (uint16_t*)d_ws;                 // 1 MB
  uint16_t* cs_lo = cs_hi + (size_t)NC * ND;         // 1 MB
  float* csq = (float*)(cs_lo + (size_t)NC * ND);    // 4 KB

  prep_centers<<<dim3(NC), dim3(64), 0, stream>>>(centers, cs_hi, cs_lo, csq);
  kmeans_fused<<<dim3(NROWS / BM), dim3(512), 0, stream>>>(x, cs_hi, cs_lo, csq,
                                                           dist, prob);
}